// Round 4
// baseline (257.536 us; speedup 1.0000x reference)
//
#include <hip/hip_runtime.h>
#include <hip/hip_bf16.h>

// B=2, S=2048, HID=1024, H=16, KVH=4, D=64, G=4
// qkv row stride 1536 (q:0..1023, k:1024..1279, v:1280..1535)

typedef short bfx8 __attribute__((ext_vector_type(8)));   // 8 bf16 (4 VGPRs)
typedef float fx4  __attribute__((ext_vector_type(4)));   // MFMA C/D 16x16
typedef float fx16 __attribute__((ext_vector_type(16)));  // MFMA C/D 32x32
typedef unsigned int ux4 __attribute__((ext_vector_type(4)));

#define DEV __device__ __forceinline__
#define ALPHA 0.18033688011112042f   // 1/sqrt(64) * log2(e), folded into Q at RoPE

DEV void load_lds16(const void* g, void* l) {
  __builtin_amdgcn_global_load_lds(
      (const __attribute__((address_space(1))) unsigned int*)g,
      (__attribute__((address_space(3))) unsigned int*)l, 16, 0, 0);
}

DEV unsigned short f2bf(float f) {
  unsigned int x = __builtin_bit_cast(unsigned int, f);
  unsigned int r = (x + 0x7fffu + ((x >> 16) & 1u)) >> 16;
  return (unsigned short)r;
}
DEV float bf2f(unsigned short u) {
  unsigned int x = ((unsigned int)u) << 16;
  return __builtin_bit_cast(float, x);
}
DEV float exp2_fast(float x) { float r; asm("v_exp_f32 %0, %1" : "=v"(r) : "v"(x)); return r; }
DEV unsigned cvtpk(float lo, float hi) {
  unsigned r; asm("v_cvt_pk_bf16_f32 %0, %1, %2" : "=v"(r) : "v"(lo), "v"(hi)); return r;
}

// ---------------- conversions ----------------

__global__ __launch_bounds__(256) void cvt_x_kernel(const float* __restrict__ x,
                                                    unsigned short* __restrict__ out) {
  int i = (blockIdx.x * 256 + threadIdx.x) * 8;
  fx4 a = *(const fx4*)(x + i);
  fx4 b = *(const fx4*)(x + i + 4);
  bfx8 r;
  r[0] = (short)f2bf(a[0]); r[1] = (short)f2bf(a[1]);
  r[2] = (short)f2bf(a[2]); r[3] = (short)f2bf(a[3]);
  r[4] = (short)f2bf(b[0]); r[5] = (short)f2bf(b[1]);
  r[6] = (short)f2bf(b[2]); r[7] = (short)f2bf(b[3]);
  *(bfx8*)(out + i) = r;
}

__global__ __launch_bounds__(256) void build_wqkvT_kernel(const float* __restrict__ wq,
                                                          const float* __restrict__ wk,
                                                          const float* __restrict__ wv,
                                                          unsigned short* __restrict__ out) {
  int tid = blockIdx.x * 256 + threadIdx.x;   // 1536*1024
  int r = tid >> 10, c = tid & 1023;
  float v;
  if (r < 1024)      v = wq[(size_t)c * 1024 + r];
  else if (r < 1280) v = wk[(size_t)c * 256 + (r - 1024)];
  else               v = wv[(size_t)c * 256 + (r - 1280)];
  out[tid] = f2bf(v);
}

__global__ __launch_bounds__(256) void build_woT_kernel(const float* __restrict__ wo,
                                                        unsigned short* __restrict__ out) {
  int tid = blockIdx.x * 256 + threadIdx.x;   // 1024*1024
  int r = tid >> 10, c = tid & 1023;
  out[tid] = f2bf(wo[(size_t)c * 1024 + r]);
}

// ---------------- RoPE (in place; q-heads pre-scaled by ALPHA) ----------------

__global__ __launch_bounds__(256) void rope_kernel(unsigned short* __restrict__ qkv,
                                                   const float* __restrict__ ct,
                                                   const float* __restrict__ st) {
  int tid = blockIdx.x * 256 + threadIdx.x;   // 4096 * 640
  int row = tid / 640;
  int rem = tid - row * 640;
  int head = rem >> 5, d = rem & 31;          // head 0..19 (16 q then 4 k), d 0..31
  int s = row & 2047;
  float c = ct[s * 64 + d], sn = st[s * 64 + d];
  float sc = (head < 16) ? ALPHA : 1.0f;
  unsigned short* p = qkv + (size_t)row * 1536 + head * 64 + d;
  float x0 = bf2f(p[0]);
  float x1 = bf2f(p[32]);
  p[0]  = f2bf((x0 * c - x1 * sn) * sc);
  p[32] = f2bf((x1 * c + x0 * sn) * sc);
}

// ---------------- V^T pre-pass: vT[b][kvh][d=64][s=2048] ----------------

__global__ __launch_bounds__(256) void vt_kernel(const unsigned short* __restrict__ qkv,
                                                 unsigned short* __restrict__ vT) {
  __shared__ __align__(16) unsigned short tile[64][72];
  const int sc = blockIdx.x;            // s-chunk 0..31 (64 rows)
  const int kvh = blockIdx.y, b = blockIdx.z;
  const int t = threadIdx.x;
  const unsigned short* src = qkv + ((size_t)b * 2048 + sc * 64) * 1536 + 1280 + kvh * 64;
#pragma unroll
  for (int p = 0; p < 2; ++p) {
    int idx = p * 256 + t;              // 512 chunks of 16B
    int row = idx >> 3, c = idx & 7;
    *(bfx8*)(&tile[row][c * 8]) = *(const bfx8*)(src + (size_t)row * 1536 + c * 8);
  }
  __syncthreads();
  unsigned short* dst = vT + ((size_t)(b * 4 + kvh) * 64) * 2048 + sc * 64;
#pragma unroll
  for (int p = 0; p < 2; ++p) {
    int idx = p * 256 + t;
    int d = idx >> 3, c = idx & 7;
    bfx8 v;
#pragma unroll
    for (int i = 0; i < 8; ++i) v[i] = (short)tile[c * 8 + i][d];
    *(bfx8*)(dst + (size_t)d * 2048 + c * 8) = v;
  }
}

// ---------------- GEMM: C[M][ldc] = A[M][K] * Bt[N][K]^T ----------------

template <bool OUT_BF16>
__global__ __launch_bounds__(256) void gemm_bt_kernel(const unsigned short* __restrict__ A,
                                                      const unsigned short* __restrict__ Bt,
                                                      void* __restrict__ Cp,
                                                      int M, int N, int K, int ldc) {
  __shared__ __align__(16) unsigned short As[128 * 32];
  __shared__ __align__(16) unsigned short Bs[128 * 32];
  const int t = threadIdx.x;
  const int l = t & 63;
  const int w = t >> 6;
  const int wm = (w >> 1) * 64, wn = (w & 1) * 64;
  const int bm = blockIdx.x, bn = blockIdx.y;
  fx4 acc[4][4] = {};

  const int ra = t >> 2;
  const int ca = t & 3;

  for (int kt = 0; kt < K; kt += 32) {
    __syncthreads();
#pragma unroll
    for (int p = 0; p < 2; ++p) {
      int rr = ra + p * 64;
      int gca = ((ca ^ ((rr >> 1) & 3)) * 8);
      load_lds16(A + (size_t)(bm * 128 + rr) * K + kt + gca, (char*)As + p * 4096 + t * 16);
      load_lds16(Bt + (size_t)(bn * 128 + rr) * K + kt + gca, (char*)Bs + p * 4096 + t * 16);
    }
    __syncthreads();

    bfx8 af[4], bfr[4];
#pragma unroll
    for (int mi = 0; mi < 4; ++mi) {
      int row = wm + mi * 16 + (l & 15);
      int ch = (l >> 4) ^ ((row >> 1) & 3);
      af[mi] = *(const bfx8*)(As + row * 32 + ch * 8);
      int rowb = wn + mi * 16 + (l & 15);
      int chb = (l >> 4) ^ ((rowb >> 1) & 3);
      bfr[mi] = *(const bfx8*)(Bs + rowb * 32 + chb * 8);
    }
#pragma unroll
    for (int mi = 0; mi < 4; ++mi)
#pragma unroll
      for (int ni = 0; ni < 4; ++ni)
        acc[mi][ni] = __builtin_amdgcn_mfma_f32_16x16x32_bf16(af[mi], bfr[ni], acc[mi][ni], 0, 0, 0);
  }

#pragma unroll
  for (int mi = 0; mi < 4; ++mi) {
    int row0 = bm * 128 + wm + mi * 16 + (l >> 4) * 4;
#pragma unroll
    for (int ni = 0; ni < 4; ++ni) {
      int col = bn * 128 + wn + ni * 16 + (l & 15);
#pragma unroll
      for (int r = 0; r < 4; ++r) {
        if (OUT_BF16)
          ((unsigned short*)Cp)[(size_t)(row0 + r) * ldc + col] = f2bf(acc[mi][ni][r]);
        else
          ((float*)Cp)[(size_t)(row0 + r) * ldc + col] = acc[mi][ni][r];
      }
    }
  }
}

// ---------------- flash attention: wave-independent, no in-loop LDS ----------------
// 2048 blocks x 64 threads (1 wave). fid -> (T', head, b) with T' = (fid + fid>>6)&63
// so CU-resident sets get spread T' (balance). Tile = 32 q rows, KVBLK = 32.
// Swapped QK^T (S^T = K*Q) and swapped PV (O^T = V^T * P^T): lane's q = l&31 everywhere.
// K frags gathered from qkv, V^T frags gathered from vT (both L2-resident); 1-deep
// register double-buffer prefetch. Defer-max (THR=8, log2 domain) skips O-rescale.

struct Frag { bfx8 kf[4]; bfx8 vf[4]; };

__global__ __launch_bounds__(64) void attn_kernel(const unsigned short* __restrict__ qkv,
                                                  const unsigned short* __restrict__ vT,
                                                  unsigned short* __restrict__ out) {
  __shared__ unsigned Ost[32 * 33];
  const int fid = blockIdx.x;
  const int uu = fid >> 6;
  const int head = uu & 15, b = uu >> 4;
  const int Tp = (fid + uu) & 63;
  const int kvh = head >> 2;
  const int l = threadIdx.x, q5 = l & 31, h = l >> 5;
  const int q0 = Tp * 32;
  const size_t bbase = (size_t)b * 2048;
  const unsigned short* base = qkv + bbase * 1536;
  // lane-fixed gather bases
  const unsigned short* kptr = base + 1024 + kvh * 64 + (size_t)q5 * 1536 + 8 * h;
  const unsigned short* vptr = vT + ((size_t)(b * 4 + kvh) * 64 + q5) * 2048 + 8 * h;

  bfx8 qf[4];
#pragma unroll
  for (int dd = 0; dd < 4; ++dd)
    qf[dd] = *(const bfx8*)(base + (size_t)(q0 + q5) * 1536 + head * 64 + dd * 16 + 8 * h);

  fx16 o[2] = {};
  float mrun = -1e30f, lrun = 0.f;
  const int nkb = Tp + 1;

  Frag fA, fB;

#define LOADF(F, KB) do {                                                        \
    const unsigned short* kq = kptr + (size_t)(KB) * (32 * 1536);                \
    F.kf[0] = *(const bfx8*)(kq);                                                \
    F.kf[1] = *(const bfx8*)(kq + 16);                                           \
    F.kf[2] = *(const bfx8*)(kq + 32);                                           \
    F.kf[3] = *(const bfx8*)(kq + 48);                                           \
    const unsigned short* vq = vptr + (KB) * 32;                                 \
    F.vf[0] = *(const bfx8*)(vq);                    /* kc0 dt0 */               \
    F.vf[1] = *(const bfx8*)(vq + 32 * 2048);        /* kc0 dt1 */               \
    F.vf[2] = *(const bfx8*)(vq + 16);               /* kc1 dt0 */               \
    F.vf[3] = *(const bfx8*)(vq + 16 + 32 * 2048);   /* kc1 dt1 */               \
  } while (0)

#define STEP(F, KB) do {                                                         \
    fx16 s = {};                                                                 \
    s = __builtin_amdgcn_mfma_f32_32x32x16_bf16(F.kf[0], qf[0], s, 0, 0, 0);     \
    s = __builtin_amdgcn_mfma_f32_32x32x16_bf16(F.kf[1], qf[1], s, 0, 0, 0);     \
    s = __builtin_amdgcn_mfma_f32_32x32x16_bf16(F.kf[2], qf[2], s, 0, 0, 0);     \
    s = __builtin_amdgcn_mfma_f32_32x32x16_bf16(F.kf[3], qf[3], s, 0, 0, 0);     \
    if ((KB) == Tp) {                                                            \
      _Pragma("unroll")                                                          \
      for (int r = 0; r < 16; ++r) {                                             \
        int kr = (r & 3) + 8 * (r >> 2) + 4 * h;                                 \
        if (kr > q5) s[r] = -1e30f;                                              \
      }                                                                          \
    }                                                                            \
    float pmax = s[0];                                                           \
    _Pragma("unroll")                                                            \
    for (int r = 1; r < 16; ++r) pmax = fmaxf(pmax, s[r]);                       \
    pmax = fmaxf(pmax, __shfl_xor(pmax, 32, 64));                                \
    if (!__all(pmax <= mrun + 8.0f)) {                                           \
      float mnew = fmaxf(mrun, pmax);                                            \
      float corr = exp2_fast(mrun - mnew);                                       \
      mrun = mnew;                                                               \
      lrun *= corr;                                                              \
      o[0] *= corr; o[1] *= corr;                                                \
    }                                                                            \
    float lt = 0.f;                                                              \
    _Pragma("unroll")                                                            \
    for (int r = 0; r < 16; ++r) { float pv = exp2_fast(s[r] - mrun); s[r] = pv; lt += pv; } \
    lt += __shfl_xor(lt, 32, 64);                                                \
    lrun += lt;                                                                  \
    unsigned U[8];                                                               \
    _Pragma("unroll")                                                            \
    for (int k8 = 0; k8 < 8; ++k8) U[k8] = cvtpk(s[2 * k8], s[2 * k8 + 1]);      \
    _Pragma("unroll")                                                            \
    for (int kc = 0; kc < 2; ++kc) {                                             \
      unsigned send0 = h ? U[4 * kc] : U[4 * kc + 2];                            \
      unsigned send1 = h ? U[4 * kc + 1] : U[4 * kc + 3];                        \
      unsigned r0 = (unsigned)__shfl_xor((int)send0, 32, 64);                    \
      unsigned r1 = (unsigned)__shfl_xor((int)send1, 32, 64);                    \
      unsigned k0 = h ? U[4 * kc + 2] : U[4 * kc];                               \
      unsigned k1 = h ? U[4 * kc + 3] : U[4 * kc + 1];                           \
      ux4 fr;                                                                    \
      fr[0] = h ? r0 : k0; fr[1] = h ? r1 : k1;                                  \
      fr[2] = h ? k0 : r0; fr[3] = h ? k1 : r1;                                  \
      bfx8 pf = __builtin_bit_cast(bfx8, fr);                                    \
      o[0] = __builtin_amdgcn_mfma_f32_32x32x16_bf16(F.vf[kc * 2], pf, o[0], 0, 0, 0);     \
      o[1] = __builtin_amdgcn_mfma_f32_32x32x16_bf16(F.vf[kc * 2 + 1], pf, o[1], 0, 0, 0); \
    }                                                                            \
  } while (0)

  LOADF(fA, 0);
  int kb = 0;
  while (true) {
    if (kb + 1 < nkb) LOADF(fB, kb + 1);
    STEP(fA, kb);
    ++kb; if (kb >= nkb) break;
    if (kb + 1 < nkb) LOADF(fA, kb + 1);
    STEP(fB, kb);
    ++kb; if (kb >= nkb) break;
  }
#undef LOADF
#undef STEP

  // ---- epilogue: O^T -> LDS transpose -> coalesced bf16 store ----
  float inv = 1.0f / lrun;
#pragma unroll
  for (int dt = 0; dt < 2; ++dt)
#pragma unroll
    for (int rp = 0; rp < 8; ++rp) {
      int r = 2 * rp;
      float a = o[dt][r] * inv, bb = o[dt][r + 1] * inv;
      int d = 32 * dt + (r & 3) + 8 * (r >> 2) + 4 * h;   // even d; pair (d, d+1)
      Ost[q5 * 33 + (d >> 1)] = cvtpk(a, bb);
    }
  __syncthreads();
  {
    int rr = l >> 1, half = l & 1;
    const unsigned* src = Ost + rr * 33 + half * 16;
    unsigned short* dst = out + (bbase + q0 + rr) * 1024 + head * 64 + half * 32;
#pragma unroll
    for (int u2 = 0; u2 < 4; ++u2) {
      ux4 v4;
      v4[0] = src[4 * u2]; v4[1] = src[4 * u2 + 1];
      v4[2] = src[4 * u2 + 2]; v4[3] = src[4 * u2 + 3];
      *(ux4*)(dst + u2 * 8) = v4;
    }
  }
}

// ---------------- launch ----------------

extern "C" void kernel_launch(void* const* d_in, const int* in_sizes, int n_in,
                              void* d_out, int out_size, void* d_ws, size_t ws_size,
                              hipStream_t stream) {
  const float* x    = (const float*)d_in[0];
  const float* cosb = (const float*)d_in[1];
  const float* sinb = (const float*)d_in[2];
  const float* wq   = (const float*)d_in[3];
  const float* wk   = (const float*)d_in[4];
  const float* wv   = (const float*)d_in[5];
  const float* wo   = (const float*)d_in[6];
  float* out = (float*)d_out;

  char* ws = (char*)d_ws;
  unsigned short* xb    = (unsigned short*)ws;                 //  8,388,608 B
  unsigned short* attn  = (unsigned short*)ws;                 //  (alias; xb dead by then)
  unsigned short* wqkvT = (unsigned short*)(ws + 8388608);     //  3,145,728 B
  unsigned short* vT    = (unsigned short*)(ws + 8388608);     //  (alias; wqkvT dead after gemm1; 2 MiB)
  unsigned short* woT   = (unsigned short*)(ws + 11534336);    //  2,097,152 B
  unsigned short* qkv   = (unsigned short*)(ws + 13631488);    // 12,582,912 B

  cvt_x_kernel<<<2048, 256, 0, stream>>>(x, xb);
  build_wqkvT_kernel<<<6144, 256, 0, stream>>>(wq, wk, wv, wqkvT);
  build_woT_kernel<<<4096, 256, 0, stream>>>(wo, woT);
  gemm_bt_kernel<true><<<dim3(32, 12), 256, 0, stream>>>(xb, wqkvT, qkv, 4096, 1536, 1024, 1536);
  rope_kernel<<<10240, 256, 0, stream>>>(qkv, cosb, sinb);
  vt_kernel<<<dim3(32, 4, 2), 256, 0, stream>>>(qkv, vT);
  attn_kernel<<<2048, 64, 0, stream>>>(qkv, vT, attn);
  gemm_bt_kernel<false><<<dim3(32, 8), 256, 0, stream>>>(attn, woT, out, 4096, 1024, 1024, 1024);
}

// Round 5
// 210.224 us; speedup vs baseline: 1.2251x; 1.2251x over previous
//
#include <hip/hip_runtime.h>
#include <hip/hip_bf16.h>

// B=2, S=2048, HID=1024, H=16, KVH=4, D=64, G=4
// qkv row stride 1536 (q:0..1023, k:1024..1279, v:1280..1535)

typedef short bfx8 __attribute__((ext_vector_type(8)));   // 8 bf16 (4 VGPRs)
typedef float fx4  __attribute__((ext_vector_type(4)));   // MFMA C/D 16x16
typedef float fx16 __attribute__((ext_vector_type(16)));  // MFMA C/D 32x32
typedef unsigned int ux4 __attribute__((ext_vector_type(4)));

#define DEV __device__ __forceinline__
#define ALPHA 0.18033688011112042f   // 1/sqrt(64) * log2(e), folded into q at GEMM1 epilogue

DEV void load_lds16(const void* g, void* l) {
  __builtin_amdgcn_global_load_lds(
      (const __attribute__((address_space(1))) unsigned int*)g,
      (__attribute__((address_space(3))) unsigned int*)l, 16, 0, 0);
}

DEV unsigned short f2bf(float f) {
  unsigned int x = __builtin_bit_cast(unsigned int, f);
  unsigned int r = (x + 0x7fffu + ((x >> 16) & 1u)) >> 16;
  return (unsigned short)r;
}
DEV float bf2f(unsigned short u) {
  unsigned int x = ((unsigned int)u) << 16;
  return __builtin_bit_cast(float, x);
}
DEV float exp2_fast(float x) { float r; asm("v_exp_f32 %0, %1" : "=v"(r) : "v"(x)); return r; }
DEV unsigned cvtpk(float lo, float hi) {
  unsigned r; asm("v_cvt_pk_bf16_f32 %0, %1, %2" : "=v"(r) : "v"(lo), "v"(hi)); return r;
}

// ---------------- x fp32 -> bf16 ----------------

__global__ __launch_bounds__(256) void cvt_x_kernel(const float* __restrict__ x,
                                                    unsigned short* __restrict__ out) {
  int i = (blockIdx.x * 256 + threadIdx.x) * 8;
  fx4 a = *(const fx4*)(x + i);
  fx4 b = *(const fx4*)(x + i + 4);
  bfx8 r;
  r[0] = (short)f2bf(a[0]); r[1] = (short)f2bf(a[1]);
  r[2] = (short)f2bf(a[2]); r[3] = (short)f2bf(a[3]);
  r[4] = (short)f2bf(b[0]); r[5] = (short)f2bf(b[1]);
  r[6] = (short)f2bf(b[2]); r[7] = (short)f2bf(b[3]);
  *(bfx8*)(out + i) = r;
}

// ---------------- coalesced LDS-tiled weight transposes (f32 -> bf16) ----------------
// out[r][c] = w[c][r]. 64x64 tiles; LDS scatter-write stride 65 (2-way max), coalesced read.

__global__ __launch_bounds__(256) void twqkv_kernel(const float* __restrict__ wq,
                                                    const float* __restrict__ wk,
                                                    const float* __restrict__ wv,
                                                    unsigned short* __restrict__ out) {
  __shared__ float tile[64 * 65];
  const int r0 = blockIdx.x * 64;   // out-row base 0..1535
  const int c0 = blockIdx.y * 64;   // k base 0..1023
  const float* src; int ncols, rofs;
  if (r0 < 1024)      { src = wq; ncols = 1024; rofs = r0; }
  else if (r0 < 1280) { src = wk; ncols = 256;  rofs = r0 - 1024; }
  else                { src = wv; ncols = 256;  rofs = r0 - 1280; }
  const int t = threadIdx.x;
#pragma unroll
  for (int p = 0; p < 4; ++p) {
    int idx = p * 256 + t;
    int cc = idx >> 4, q4 = idx & 15;   // src row c0+cc, src cols rofs+q4*4..+3
    fx4 v = *(const fx4*)(src + (size_t)(c0 + cc) * ncols + rofs + q4 * 4);
#pragma unroll
    for (int i = 0; i < 4; ++i) tile[(q4 * 4 + i) * 65 + cc] = v[i];
  }
  __syncthreads();
#pragma unroll
  for (int p = 0; p < 2; ++p) {
    int idx = p * 256 + t;
    int rr = idx >> 3, c8 = idx & 7;
    bfx8 v8;
#pragma unroll
    for (int i = 0; i < 8; ++i) v8[i] = (short)f2bf(tile[rr * 65 + c8 * 8 + i]);
    *(bfx8*)(out + (size_t)(r0 + rr) * 1024 + c0 + c8 * 8) = v8;
  }
}

__global__ __launch_bounds__(256) void two_kernel(const float* __restrict__ wo,
                                                  unsigned short* __restrict__ out) {
  __shared__ float tile[64 * 65];
  const int r0 = blockIdx.x * 64, c0 = blockIdx.y * 64;
  const int t = threadIdx.x;
#pragma unroll
  for (int p = 0; p < 4; ++p) {
    int idx = p * 256 + t;
    int cc = idx >> 4, q4 = idx & 15;
    fx4 v = *(const fx4*)(wo + (size_t)(c0 + cc) * 1024 + r0 + q4 * 4);
#pragma unroll
    for (int i = 0; i < 4; ++i) tile[(q4 * 4 + i) * 65 + cc] = v[i];
  }
  __syncthreads();
#pragma unroll
  for (int p = 0; p < 2; ++p) {
    int idx = p * 256 + t;
    int rr = idx >> 3, c8 = idx & 7;
    bfx8 v8;
#pragma unroll
    for (int i = 0; i < 8; ++i) v8[i] = (short)f2bf(tile[rr * 65 + c8 * 8 + i]);
    *(bfx8*)(out + (size_t)(r0 + rr) * 1024 + c0 + c8 * 8) = v8;
  }
}

// ---------------- V^T pre-pass: vT[b][kvh][d=64][s=2048] ----------------

__global__ __launch_bounds__(256) void vt_kernel(const unsigned short* __restrict__ qkv,
                                                 unsigned short* __restrict__ vT) {
  __shared__ __align__(16) unsigned short tile[64][72];
  const int sc = blockIdx.x;            // s-chunk 0..31
  const int kvh = blockIdx.y, b = blockIdx.z;
  const int t = threadIdx.x;
  const unsigned short* src = qkv + ((size_t)b * 2048 + sc * 64) * 1536 + 1280 + kvh * 64;
#pragma unroll
  for (int p = 0; p < 2; ++p) {
    int idx = p * 256 + t;
    int row = idx >> 3, c = idx & 7;
    *(bfx8*)(&tile[row][c * 8]) = *(const bfx8*)(src + (size_t)row * 1536 + c * 8);
  }
  __syncthreads();
  unsigned short* dst = vT + ((size_t)(b * 4 + kvh) * 64) * 2048 + sc * 64;
#pragma unroll
  for (int p = 0; p < 2; ++p) {
    int idx = p * 256 + t;
    int d = idx >> 3, c = idx & 7;
    bfx8 v;
#pragma unroll
    for (int i = 0; i < 8; ++i) v[i] = (short)tile[c * 8 + i][d];
    *(bfx8*)(dst + (size_t)d * 2048 + c * 8) = v;
  }
}

// ---------------- GEMM: C[M][ldc] = A[M][K] * Bt[N][K]^T (optional fused RoPE) ----------------

template <bool OUT_BF16, bool FUSE_ROPE>
__global__ __launch_bounds__(256) void gemm_bt_kernel(const unsigned short* __restrict__ A,
                                                      const unsigned short* __restrict__ Bt,
                                                      void* __restrict__ Cp,
                                                      int M, int N, int K, int ldc,
                                                      const float* __restrict__ ct,
                                                      const float* __restrict__ st) {
  __shared__ __align__(16) unsigned short As[128 * 32];
  __shared__ __align__(16) unsigned short Bs[128 * 32];
  const int t = threadIdx.x;
  const int l = t & 63;
  const int w = t >> 6;
  const int wm = (w >> 1) * 64, wn = (w & 1) * 64;
  const int bm = blockIdx.x, bn = blockIdx.y;
  fx4 acc[4][4] = {};

  const int ra = t >> 2;
  const int ca = t & 3;

  for (int kt = 0; kt < K; kt += 32) {
    __syncthreads();
#pragma unroll
    for (int p = 0; p < 2; ++p) {
      int rr = ra + p * 64;
      int gca = ((ca ^ ((rr >> 1) & 3)) * 8);
      load_lds16(A + (size_t)(bm * 128 + rr) * K + kt + gca, (char*)As + p * 4096 + t * 16);
      load_lds16(Bt + (size_t)(bn * 128 + rr) * K + kt + gca, (char*)Bs + p * 4096 + t * 16);
    }
    __syncthreads();

    bfx8 af[4], bfr[4];
#pragma unroll
    for (int mi = 0; mi < 4; ++mi) {
      int row = wm + mi * 16 + (l & 15);
      int ch = (l >> 4) ^ ((row >> 1) & 3);
      af[mi] = *(const bfx8*)(As + row * 32 + ch * 8);
      int rowb = wn + mi * 16 + (l & 15);
      int chb = (l >> 4) ^ ((rowb >> 1) & 3);
      bfr[mi] = *(const bfx8*)(Bs + rowb * 32 + chb * 8);
    }
#pragma unroll
    for (int mi = 0; mi < 4; ++mi)
#pragma unroll
      for (int ni = 0; ni < 4; ++ni)
        acc[mi][ni] = __builtin_amdgcn_mfma_f32_16x16x32_bf16(af[mi], bfr[ni], acc[mi][ni], 0, 0, 0);
  }

  const int colbase = bn * 128 + wn;              // head-aligned 64-col window
  if (FUSE_ROPE && colbase < 1280) {
    // rope pair: (d, d+32) = (acc[mi][ni], acc[mi][ni+2]), ni in {0,1}; q-cols get ALPHA
    const float qsc = (colbase < 1024) ? ALPHA : 1.0f;
    unsigned short* Cb = (unsigned short*)Cp;
#pragma unroll
    for (int mi = 0; mi < 4; ++mi) {
      int row0 = bm * 128 + wm + mi * 16 + (l >> 4) * 4;
#pragma unroll
      for (int r = 0; r < 4; ++r) {
        int row = row0 + r, s = row & 2047;
#pragma unroll
        for (int ni = 0; ni < 2; ++ni) {
          int d = ni * 16 + (l & 15);
          float c = ct[s * 64 + d], sn = st[s * 64 + d];
          float x0 = acc[mi][ni][r], x1 = acc[mi][ni + 2][r];
          Cb[(size_t)row * ldc + colbase + d]      = f2bf((x0 * c - x1 * sn) * qsc);
          Cb[(size_t)row * ldc + colbase + d + 32] = f2bf((x1 * c + x0 * sn) * qsc);
        }
      }
    }
  } else {
#pragma unroll
    for (int mi = 0; mi < 4; ++mi) {
      int row0 = bm * 128 + wm + mi * 16 + (l >> 4) * 4;
#pragma unroll
      for (int ni = 0; ni < 4; ++ni) {
        int col = colbase + ni * 16 + (l & 15);
#pragma unroll
        for (int r = 0; r < 4; ++r) {
          if (OUT_BF16)
            ((unsigned short*)Cp)[(size_t)(row0 + r) * ldc + col] = f2bf(acc[mi][ni][r]);
          else
            ((float*)Cp)[(size_t)(row0 + r) * ldc + col] = acc[mi][ni][r];
        }
      }
    }
  }
}

// ---------------- flash attention: paired causal tiles, uniform 65 steps/wave ----------------
// 1024 blocks x 64 threads (1 wave). fid -> (pid, head, b); wave processes q-tiles
// t0=pid (pid+1 kv-steps) then t1=63-pid (64-pid steps) -> exactly 65 steps each.
// Swapped QK^T (S^T = K*Q) + swapped PV (O^T = V^T*P^T): lane's q = l&31 everywhere.
// K/V^T fragments gathered from global (L2-resident), 1-deep register double-buffer.

struct Frag { bfx8 kf[4]; bfx8 vf[4]; };

__global__ __launch_bounds__(64) void attn_kernel(const unsigned short* __restrict__ qkv,
                                                  const unsigned short* __restrict__ vT,
                                                  unsigned short* __restrict__ out) {
  __shared__ unsigned Ost[32 * 33];
  const int fid = blockIdx.x;
  const int pid = fid & 31;
  const int uu = fid >> 5;
  const int head = uu & 15, b = uu >> 4;
  const int kvh = head >> 2;
  const int l = threadIdx.x, q5 = l & 31, h = l >> 5;
  const size_t bbase = (size_t)b * 2048;
  const unsigned short* base = qkv + bbase * 1536;
  const unsigned short* kptr = base + 1024 + kvh * 64 + (size_t)q5 * 1536 + 8 * h;
  const unsigned short* vptr = vT + ((size_t)(b * 4 + kvh) * 64 + q5) * 2048 + 8 * h;

  Frag fA, fB;

#define LOADF(F, KB) do {                                                        \
    const unsigned short* kq = kptr + (size_t)(KB) * (32 * 1536);                \
    F.kf[0] = *(const bfx8*)(kq);                                                \
    F.kf[1] = *(const bfx8*)(kq + 16);                                           \
    F.kf[2] = *(const bfx8*)(kq + 32);                                           \
    F.kf[3] = *(const bfx8*)(kq + 48);                                           \
    const unsigned short* vq = vptr + (KB) * 32;                                 \
    F.vf[0] = *(const bfx8*)(vq);                                                \
    F.vf[1] = *(const bfx8*)(vq + 32 * 2048);                                    \
    F.vf[2] = *(const bfx8*)(vq + 16);                                           \
    F.vf[3] = *(const bfx8*)(vq + 16 + 32 * 2048);                               \
  } while (0)

#define STEP(F, KB) do {                                                         \
    fx16 s = {};                                                                 \
    s = __builtin_amdgcn_mfma_f32_32x32x16_bf16(F.kf[0], qf[0], s, 0, 0, 0);     \
    s = __builtin_amdgcn_mfma_f32_32x32x16_bf16(F.kf[1], qf[1], s, 0, 0, 0);     \
    s = __builtin_amdgcn_mfma_f32_32x32x16_bf16(F.kf[2], qf[2], s, 0, 0, 0);     \
    s = __builtin_amdgcn_mfma_f32_32x32x16_bf16(F.kf[3], qf[3], s, 0, 0, 0);     \
    if ((KB) == Tp) {                                                            \
      _Pragma("unroll")                                                          \
      for (int r = 0; r < 16; ++r) {                                             \
        int kr = (r & 3) + 8 * (r >> 2) + 4 * h;                                 \
        if (kr > q5) s[r] = -1e30f;                                              \
      }                                                                          \
    }                                                                            \
    float pmax = s[0];                                                           \
    _Pragma("unroll")                                                            \
    for (int r = 1; r < 16; ++r) pmax = fmaxf(pmax, s[r]);                       \
    pmax = fmaxf(pmax, __shfl_xor(pmax, 32, 64));                                \
    if (!__all(pmax <= mrun + 8.0f)) {                                           \
      float mnew = fmaxf(mrun, pmax);                                            \
      float corr = exp2_fast(mrun - mnew);                                       \
      mrun = mnew;                                                               \
      lrun *= corr;                                                              \
      o[0] *= corr; o[1] *= corr;                                                \
    }                                                                            \
    float lt = 0.f;                                                              \
    _Pragma("unroll")                                                            \
    for (int r = 0; r < 16; ++r) { float pv = exp2_fast(s[r] - mrun); s[r] = pv; lt += pv; } \
    lt += __shfl_xor(lt, 32, 64);                                                \
    lrun += lt;                                                                  \
    unsigned U[8];                                                               \
    _Pragma("unroll")                                                            \
    for (int k8 = 0; k8 < 8; ++k8) U[k8] = cvtpk(s[2 * k8], s[2 * k8 + 1]);      \
    _Pragma("unroll")                                                            \
    for (int kc = 0; kc < 2; ++kc) {                                             \
      unsigned send0 = h ? U[4 * kc] : U[4 * kc + 2];                            \
      unsigned send1 = h ? U[4 * kc + 1] : U[4 * kc + 3];                        \
      unsigned r0 = (unsigned)__shfl_xor((int)send0, 32, 64);                    \
      unsigned r1 = (unsigned)__shfl_xor((int)send1, 32, 64);                    \
      unsigned k0 = h ? U[4 * kc + 2] : U[4 * kc];                               \
      unsigned k1 = h ? U[4 * kc + 3] : U[4 * kc + 1];                           \
      ux4 fr;                                                                    \
      fr[0] = h ? r0 : k0; fr[1] = h ? r1 : k1;                                  \
      fr[2] = h ? k0 : r0; fr[3] = h ? k1 : r1;                                  \
      bfx8 pf = __builtin_bit_cast(bfx8, fr);                                    \
      o[0] = __builtin_amdgcn_mfma_f32_32x32x16_bf16(F.vf[kc * 2], pf, o[0], 0, 0, 0);     \
      o[1] = __builtin_amdgcn_mfma_f32_32x32x16_bf16(F.vf[kc * 2 + 1], pf, o[1], 0, 0, 0); \
    }                                                                            \
  } while (0)

#pragma unroll 1
  for (int sel = 0; sel < 2; ++sel) {
    const int Tp = sel ? (63 - pid) : pid;
    const int q0 = Tp * 32;
    const int nkb = Tp + 1;

    bfx8 qf[4];
#pragma unroll
    for (int dd = 0; dd < 4; ++dd)
      qf[dd] = *(const bfx8*)(base + (size_t)(q0 + q5) * 1536 + head * 64 + dd * 16 + 8 * h);

    fx16 o[2] = {};
    float mrun = -1e30f, lrun = 0.f;

    LOADF(fA, 0);
    int kb = 0;
    while (true) {
      if (kb + 1 < nkb) LOADF(fB, kb + 1);
      STEP(fA, kb);
      ++kb; if (kb >= nkb) break;
      if (kb + 1 < nkb) LOADF(fA, kb + 1);
      STEP(fB, kb);
      ++kb; if (kb >= nkb) break;
    }

    // epilogue: O^T -> LDS transpose -> coalesced bf16 store
    __syncthreads();
    float inv = 1.0f / lrun;
#pragma unroll
    for (int dt = 0; dt < 2; ++dt)
#pragma unroll
      for (int rp = 0; rp < 8; ++rp) {
        int r = 2 * rp;
        float a = o[dt][r] * inv, bb = o[dt][r + 1] * inv;
        int d = 32 * dt + (r & 3) + 8 * (r >> 2) + 4 * h;   // even d; pair (d, d+1)
        Ost[q5 * 33 + (d >> 1)] = cvtpk(a, bb);
      }
    __syncthreads();
    {
      int rr = l >> 1, half = l & 1;
      const unsigned* src = Ost + rr * 33 + half * 16;
      unsigned short* dst = out + (bbase + q0 + rr) * 1024 + head * 64 + half * 32;
#pragma unroll
      for (int u2 = 0; u2 < 4; ++u2) {
        ux4 v4;
        v4[0] = src[4 * u2]; v4[1] = src[4 * u2 + 1];
        v4[2] = src[4 * u2 + 2]; v4[3] = src[4 * u2 + 3];
        *(ux4*)(dst + u2 * 8) = v4;
      }
    }
  }
#undef LOADF
#undef STEP
}

// ---------------- launch ----------------

extern "C" void kernel_launch(void* const* d_in, const int* in_sizes, int n_in,
                              void* d_out, int out_size, void* d_ws, size_t ws_size,
                              hipStream_t stream) {
  const float* x    = (const float*)d_in[0];
  const float* cosb = (const float*)d_in[1];
  const float* sinb = (const float*)d_in[2];
  const float* wq   = (const float*)d_in[3];
  const float* wk   = (const float*)d_in[4];
  const float* wv   = (const float*)d_in[5];
  const float* wo   = (const float*)d_in[6];
  float* out = (float*)d_out;

  char* ws = (char*)d_ws;
  unsigned short* xb    = (unsigned short*)ws;                 //  8,388,608 B
  unsigned short* attn  = (unsigned short*)ws;                 //  (alias; xb dead by then)
  unsigned short* wqkvT = (unsigned short*)(ws + 8388608);     //  3,145,728 B
  unsigned short* vT    = (unsigned short*)(ws + 8388608);     //  (alias; wqkvT dead after gemm1)
  unsigned short* woT   = (unsigned short*)(ws + 11534336);    //  2,097,152 B
  unsigned short* qkv   = (unsigned short*)(ws + 13631488);    // 12,582,912 B

  cvt_x_kernel<<<2048, 256, 0, stream>>>(x, xb);
  twqkv_kernel<<<dim3(24, 16), 256, 0, stream>>>(wq, wk, wv, wqkvT);
  two_kernel<<<dim3(16, 16), 256, 0, stream>>>(wo, woT);
  gemm_bt_kernel<true, true><<<dim3(32, 12), 256, 0, stream>>>(xb, wqkvT, qkv, 4096, 1536, 1024, 1536, cosb, sinb);
  vt_kernel<<<dim3(32, 4, 2), 256, 0, stream>>>(qkv, vT);
  attn_kernel<<<1024, 64, 0, stream>>>(qkv, vT, attn);
  gemm_bt_kernel<false, false><<<dim3(32, 8), 256, 0, stream>>>(attn, woT, out, 4096, 1024, 1024, 1024, nullptr, nullptr);
}